// Round 4
// baseline (1906.264 us; speedup 1.0000x reference)
//
#include <hip/hip_runtime.h>

typedef __attribute__((ext_vector_type(4))) float f32x4;
typedef __attribute__((ext_vector_type(8))) short bf16x8;

#define BATCH 8
#define MDIM 4096
#define KDIM 4096
#define NDIM 128
#define NT 32      // K tiles of 128
#define BLOCK 256
#define REPS 4     // DIAGNOSTIC: x4 internal repeat so this dispatch cracks rocprof top-5

__device__ __forceinline__ ushort f2bf(float f) {
  unsigned u = __float_as_uint(f);
  unsigned r = (u + 0x7fffu + ((u >> 16) & 1u)) >> 16;  // RNE
  return (ushort)r;
}

// ---------------- pre-kernel: B [b][k][n] fp32 -> Bt [b][n][k] bf16 ----------------
__global__ __launch_bounds__(256) void conv_b(const float* __restrict__ b,
                                              ushort* __restrict__ bt) {
  int t = blockIdx.x * 256 + threadIdx.x;   // 0 .. 8*128*512-1
  int n  = t & (NDIM - 1);
  int k8 = (t >> 7) & 511;
  int bb = t >> 16;
  int k = k8 * 8;
  const float* src = b + ((size_t)bb * KDIM + k) * NDIM + n;  // b[bb][k][n]
  ushort r[8];
#pragma unroll
  for (int j = 0; j < 8; ++j) r[j] = f2bf(src[(size_t)j * NDIM]);
  ushort* dst = bt + ((size_t)bb * NDIM + n) * KDIM + k;
  *reinterpret_cast<uint4*>(dst) = *reinterpret_cast<const uint4*>(r);
}

// ---------------- main kernel: barrier-free, per-wave 16x128 strip, 4-deep pipeline ----------------
__global__ __launch_bounds__(BLOCK, 2) void sparse_bmm(
    const float* __restrict__ a, const ushort* __restrict__ bt,
    float* __restrict__ c) {
  const int tid  = threadIdx.x;
  const int lane = tid & 63;
  const int wave = tid >> 6;              // 0..3
  const int bb = blockIdx.x & 7;          // batch -> XCD affinity (Bt slice L2-pinned)
  const int mt = blockIdx.x >> 3;         // 0..63
  const int m0 = mt * 64 + wave * 16;     // wave's 16-row strip

  const int lr = lane & 15;   // A row-in-16 / B col-in-16 / C col-in-16
  const int lk = lane >> 4;   // k-group 0..3 (8 elems each)

  // lane-fixed base pointers: fragment elements are 8 contiguous along k
  const float*  arow = a  + ((size_t)(bb * MDIM + m0 + lr)) * KDIM + lk * 8;
  const ushort* brow = bt + ((size_t)(bb * NDIM + lr)) * KDIM + lk * 8;
  float* crow = c + ((size_t)(bb * MDIM + m0)) * NDIM;

  f32x4 acc[8];
  f32x4 ra0[8], ra1[8], ra2[8], ra3[8];   // statically-named 4-deep buffers (rule #20)

  auto loadA = [&](f32x4 (&ra)[8], int kt) {
    const float* p = arow + kt * 128;
#pragma unroll
    for (int kk = 0; kk < 4; ++kk) {
      ra[kk * 2]     = __builtin_nontemporal_load(reinterpret_cast<const f32x4*>(p + kk * 32));
      ra[kk * 2 + 1] = __builtin_nontemporal_load(reinterpret_cast<const f32x4*>(p + kk * 32 + 4));
    }
  };

  auto process = [&](f32x4 (&ra)[8], int kt) {
    unsigned nz = 0;
#pragma unroll
    for (int i = 0; i < 8; ++i)
      nz |= __float_as_uint(ra[i][0]) | __float_as_uint(ra[i][1]) |
            __float_as_uint(ra[i][2]) | __float_as_uint(ra[i][3]);
    nz &= 0x7fffffffu;                    // -0.0 counts as zero
    if (!__any((int)(nz != 0u))) return;  // whole 16x128 wave-tile zero -> skip

    bf16x8 af[4];
#pragma unroll
    for (int kk = 0; kk < 4; ++kk) {
      f32x4 v0 = ra[kk * 2], v1 = ra[kk * 2 + 1];
      ushort h[8];
      h[0] = f2bf(v0[0]); h[1] = f2bf(v0[1]); h[2] = f2bf(v0[2]); h[3] = f2bf(v0[3]);
      h[4] = f2bf(v1[0]); h[5] = f2bf(v1[1]); h[6] = f2bf(v1[2]); h[7] = f2bf(v1[3]);
      af[kk] = *reinterpret_cast<bf16x8*>(h);
    }

    const ushort* bp = brow + kt * 128;
#pragma unroll
    for (int kk = 0; kk < 4; ++kk) {
      bf16x8 bf[8];
#pragma unroll
      for (int ni = 0; ni < 8; ++ni)
        bf[ni] = *reinterpret_cast<const bf16x8*>(bp + (size_t)ni * 16 * KDIM + kk * 32);
#pragma unroll
      for (int ni = 0; ni < 8; ++ni)
        acc[ni] = __builtin_amdgcn_mfma_f32_16x16x32_bf16(af[kk], bf[ni], acc[ni], 0, 0, 0);
    }
  };

  for (int rep = 0; rep < REPS; ++rep) {
#pragma unroll
    for (int ni = 0; ni < 8; ++ni)
#pragma unroll
      for (int e = 0; e < 4; ++e) acc[ni][e] = 0.f;

    loadA(ra0, 0);
    loadA(ra1, 1);
    loadA(ra2, 2);
    loadA(ra3, 3);
#pragma unroll
    for (int kt = 0; kt < NT; kt += 4) {
      process(ra0, kt);
      if (kt + 4 < NT) loadA(ra0, kt + 4);
      process(ra1, kt + 1);
      if (kt + 5 < NT) loadA(ra1, kt + 5);
      process(ra2, kt + 2);
      if (kt + 6 < NT) loadA(ra2, kt + 6);
      process(ra3, kt + 3);
      if (kt + 7 < NT) loadA(ra3, kt + 7);
    }

    // epilogue: C frag mapping col = lane&15, row = (lane>>4)*4 + j  [m89-verified]
#pragma unroll
    for (int ni = 0; ni < 8; ++ni)
#pragma unroll
      for (int j = 0; j < 4; ++j) {
        int m = lk * 4 + j;
        int n = ni * 16 + lr;
        __builtin_nontemporal_store(acc[ni][j], crow + (size_t)m * NDIM + n);
      }
  }
}

extern "C" void kernel_launch(void* const* d_in, const int* in_sizes, int n_in,
                              void* d_out, int out_size, void* d_ws, size_t ws_size,
                              hipStream_t stream) {
  const float* a = (const float*)d_in[0];   // [8][4096][4096] fp32
  const float* b = (const float*)d_in[1];   // [8][4096][128]  fp32
  float* out = (float*)d_out;               // [8][4096][128]  fp32
  ushort* bt = (ushort*)d_ws;               // [8][128][4096]  bf16 (8.4 MB)

  conv_b<<<2048, 256, 0, stream>>>(b, bt);
  sparse_bmm<<<BATCH * (MDIM / 64), BLOCK, 0, stream>>>(a, bt, out);
}

// Round 6
// 796.824 us; speedup vs baseline: 2.3923x; 2.3923x over previous
//
#include <hip/hip_runtime.h>

typedef __attribute__((ext_vector_type(4))) float f32x4;
typedef __attribute__((ext_vector_type(8))) short bf16x8;

#define BATCH 8
#define MDIM 4096
#define KDIM 4096
#define NDIM 128
#define MT 32      // M tiles of 128
#define NT 32      // K tiles of 128
#define BLOCK 256

__device__ __forceinline__ ushort f2bf(float f) {
  unsigned u = __float_as_uint(f);
  unsigned r = (u + 0x7fffu + ((u >> 16) & 1u)) >> 16;  // RNE
  return (ushort)r;
}

__device__ __forceinline__ unsigned au(float f) { return __float_as_uint(f); }

// ---------------- kernel 0: B [b][k][n] fp32 -> Bt [b][n][k] bf16 ----------------
__global__ __launch_bounds__(256) void conv_b(const float* __restrict__ b,
                                              ushort* __restrict__ bt) {
  int t = blockIdx.x * 256 + threadIdx.x;
  int n  = t & (NDIM - 1);
  int k8 = (t >> 7) & 511;
  int bb = t >> 16;
  int k = k8 * 8;
  const float* src = b + ((size_t)bb * KDIM + k) * NDIM + n;
  ushort r[8];
#pragma unroll
  for (int j = 0; j < 8; ++j) r[j] = f2bf(src[(size_t)j * NDIM]);
  ushort* dst = bt + ((size_t)bb * NDIM + n) * KDIM + k;
  *reinterpret_cast<uint4*>(dst) = *reinterpret_cast<const uint4*>(r);
}

// ---------------- kernel 1: branch-free A scan ----------------
// One block per 128x128 tile: OR magnitude bits -> flag; bf16-copy nonzero tiles.
__global__ __launch_bounds__(256) void scan_a(const float* __restrict__ a,
                                              ushort* __restrict__ abf,
                                              int* __restrict__ flags) {
  __shared__ int s_nz;
  const int t = threadIdx.x;
  const int kt = blockIdx.x & 31;
  const int mt = (blockIdx.x >> 5) & 31;
  const int bb = blockIdx.x >> 10;

  if (t == 0) s_nz = 0;
  __syncthreads();

  const size_t base = ((size_t)(bb * MDIM + mt * 128)) * KDIM + (size_t)kt * 128;
  const int r0 = t >> 5;    // row 0..7 (per pass of 8 rows)
  const int f4 = t & 31;    // float4 index within the 128-col row
  const float* ap = a + base + (size_t)r0 * KDIM + f4 * 4;

  f32x4 v[16];
  unsigned nz = 0;
#pragma unroll
  for (int p = 0; p < 16; ++p) {
    v[p] = *reinterpret_cast<const f32x4*>(ap + (size_t)p * 8 * KDIM);
    nz |= au(v[p][0]) | au(v[p][1]) | au(v[p][2]) | au(v[p][3]);
  }
  nz &= 0x7fffffffu;                       // -0.0 counts as zero
  if (nz) atomicOr(&s_nz, 1);
  __syncthreads();
  const int anynz = s_nz;
  if (t == 0) flags[blockIdx.x] = anynz;   // flag idx = (bb*32 + mt)*32 + kt
  if (!anynz) return;

  ushort* op = abf + base + (size_t)r0 * KDIM + f4 * 4;
#pragma unroll
  for (int p = 0; p < 16; ++p) {
    ushort4 h;
    h.x = f2bf(v[p][0]); h.y = f2bf(v[p][1]); h.z = f2bf(v[p][2]); h.w = f2bf(v[p][3]);
    *reinterpret_cast<ushort4*>(op + (size_t)p * 8 * KDIM) = h;
  }
}

// ---------------- kernel 2: flag-driven GEMM over nonzero tiles only ----------------
__global__ __launch_bounds__(BLOCK) void sparse_gemm(
    const ushort* __restrict__ abf, const ushort* __restrict__ bt,
    const int* __restrict__ flags, float* __restrict__ c) {
  const int tid  = threadIdx.x;
  const int lane = tid & 63;
  const int wave = tid >> 6;              // 0..3
  const int bb   = blockIdx.x & 7;        // batch -> XCD affinity (Bt L2-pinned)
  const int mt64 = blockIdx.x >> 3;       // 0..63
  const int m0   = mt64 * 64 + wave * 16;
  const int lr = lane & 15;
  const int lk = lane >> 4;

  const ushort* arow = abf + ((size_t)(bb * MDIM + m0 + lr)) * KDIM + lk * 8;
  const ushort* brow = bt  + ((size_t)(bb * NDIM + lr)) * KDIM + lk * 8;
  const int* fl = flags + (bb * MT + (mt64 >> 1)) * NT;

  // nonzero-kt bitmask, built before touching any data (uniform SGPR loop)
  int f = (lane < 32) ? fl[lane] : 0;
  unsigned long long bal = __ballot(f != 0);
  unsigned mask = __builtin_amdgcn_readfirstlane((unsigned)(bal & 0xffffffffu));

  f32x4 acc[8];
#pragma unroll
  for (int ni = 0; ni < 8; ++ni)
#pragma unroll
    for (int e = 0; e < 4; ++e) acc[ni][e] = 0.f;

  while (mask) {
    const int kt = __builtin_ctz(mask);
    mask &= mask - 1;

    const ushort* ap = arow + kt * 128;
    bf16x8 af[4];
#pragma unroll
    for (int kk = 0; kk < 4; ++kk)
      af[kk] = *reinterpret_cast<const bf16x8*>(ap + kk * 32);

    const ushort* bp = brow + kt * 128;
#pragma unroll
    for (int kk = 0; kk < 4; ++kk) {
      bf16x8 bf[8];
#pragma unroll
      for (int ni = 0; ni < 8; ++ni)
        bf[ni] = *reinterpret_cast<const bf16x8*>(bp + (size_t)ni * 16 * KDIM + kk * 32);
#pragma unroll
      for (int ni = 0; ni < 8; ++ni)
        acc[ni] = __builtin_amdgcn_mfma_f32_16x16x32_bf16(af[kk], bf[ni], acc[ni], 0, 0, 0);
    }
  }

  // epilogue: C frag mapping col = lane&15, row = (lane>>4)*4 + j  [m89-verified]
  float* crow = c + ((size_t)(bb * MDIM + m0)) * NDIM;
#pragma unroll
  for (int ni = 0; ni < 8; ++ni)
#pragma unroll
    for (int j = 0; j < 4; ++j) {
      int m = lk * 4 + j;
      int n = ni * 16 + lr;
      crow[(size_t)m * NDIM + n] = acc[ni][j];
    }
}

extern "C" void kernel_launch(void* const* d_in, const int* in_sizes, int n_in,
                              void* d_out, int out_size, void* d_ws, size_t ws_size,
                              hipStream_t stream) {
  const float* a = (const float*)d_in[0];   // [8][4096][4096] fp32
  const float* b = (const float*)d_in[1];   // [8][4096][128]  fp32
  float* out = (float*)d_out;               // [8][4096][128]  fp32

  // workspace layout
  ushort* bt  = (ushort*)d_ws;                                  // 8.4 MB
  ushort* abf = bt + (size_t)BATCH * NDIM * KDIM;               // 268 MB
  int* flags  = (int*)(abf + (size_t)BATCH * MDIM * KDIM);      // 32 KB

  conv_b<<<2048, 256, 0, stream>>>(b, bt);
  scan_a<<<BATCH * MT * NT, 256, 0, stream>>>(a, abf, flags);
  sparse_gemm<<<BATCH * (MDIM / 64), BLOCK, 0, stream>>>(abf, bt, flags, out);
}